// Round 1
// baseline (2701.278 us; speedup 1.0000x reference)
//
#include <hip/hip_runtime.h>
#include <hip/hip_bf16.h>

#define H_DIM 2048
#define I_DIM 768
#define NEXP 64
#define TOPK 8
#define NTOK 1024   // B*S

// ---------------- workspace layout (bytes) ----------------
// topk_idx : int  [NTOK*TOPK]            @ 0        (32768 B)
// topk_w   : float[NTOK*TOPK]            @ 32768    (32768 B)
// counts   : int  [NEXP]                 @ 65536    (256 B)
// offsets  : int  [NEXP]                 @ 65792    (256 B)
// lists    : int  [NEXP*NTOK]            @ 66048    (262144 B)
// wlist    : float[NEXP*NTOK]            @ 328192   (262144 B)
// hmid     : float[NTOK*TOPK * I_DIM]    @ 590336   (25165824 B)
// total ~ 25.8 MB

__global__ void zero_kernel(float* p, int n) {
    int i = blockIdx.x * blockDim.x + threadIdx.x;
    if (i < n) p[i] = 0.f;
}

// one block per token, 64 threads (one per expert)
__global__ __launch_bounds__(64) void router_kernel(
    const float* __restrict__ x, const float* __restrict__ Wr,
    int* __restrict__ topk_idx, float* __restrict__ topk_w)
{
    const int t = blockIdx.x;
    const int e = threadIdx.x;           // 0..63, lane id
    __shared__ float xs[H_DIM];

    const float* xrow = x + (size_t)t * H_DIM;
    #pragma unroll
    for (int m = 0; m < H_DIM / 64; ++m) xs[m * 64 + e] = xrow[m * 64 + e];
    __syncthreads();

    float acc = 0.f;
    #pragma unroll 8
    for (int h = 0; h < H_DIM; ++h) acc += xs[h] * Wr[(size_t)h * NEXP + e];

    // wave softmax over 64 lanes
    float m = acc;
    #pragma unroll
    for (int o = 32; o > 0; o >>= 1) m = fmaxf(m, __shfl_xor(m, o));
    float p = __expf(acc - m);
    float s = p;
    #pragma unroll
    for (int o = 32; o > 0; o >>= 1) s += __shfl_xor(s, o);
    float prob = p / s;

    // iterative top-8 (value desc, index asc on ties -> matches lax.top_k)
    float myp = prob;
    float kw[TOPK];
    int   kid[TOPK];
    float wsum = 0.f;
    #pragma unroll
    for (int k = 0; k < TOPK; ++k) {
        float v = myp; int bi = e;
        #pragma unroll
        for (int o = 32; o > 0; o >>= 1) {
            float ov = __shfl_xor(v, o);
            int   oi = __shfl_xor(bi, o);
            if (ov > v || (ov == v && oi < bi)) { v = ov; bi = oi; }
        }
        kw[k] = v; kid[k] = bi; wsum += v;
        if (e == bi) myp = -1.f;   // remove from candidates
    }
    if (e == 0) {
        float inv = 1.f / wsum;
        #pragma unroll
        for (int k = 0; k < TOPK; ++k) {
            topk_idx[t * TOPK + k] = kid[k];
            topk_w[t * TOPK + k]   = kw[k] * inv;
        }
    }
}

// one wave per expert; deterministic ordered compaction
__global__ __launch_bounds__(64) void listbuild_kernel(
    const int* __restrict__ topk_idx, const float* __restrict__ topk_w,
    int* __restrict__ counts, int* __restrict__ lists, float* __restrict__ wlist)
{
    const int e = blockIdx.x;
    const int lane = threadIdx.x;
    int n = 0;
    for (int base = 0; base < NTOK * TOPK; base += 64) {
        int s = base + lane;
        int idx = topk_idx[s];
        bool match = (idx == e);
        unsigned long long mask = __ballot(match);
        int pre = __popcll(mask & ((1ull << lane) - 1ull));
        if (match) {
            lists[e * NTOK + n + pre] = s >> 3;       // token id
            wlist[e * NTOK + n + pre] = topk_w[s];
        }
        n += __popcll(mask);
    }
    if (lane == 0) counts[e] = n;
}

__global__ __launch_bounds__(64) void scan_kernel(
    const int* __restrict__ counts, int* __restrict__ offsets)
{
    int e = threadIdx.x;
    int v = counts[e];
    int xacc = v;
    #pragma unroll
    for (int o = 1; o < 64; o <<= 1) {
        int y = __shfl_up(xacc, o);
        if (e >= o) xacc += y;
    }
    offsets[e] = xacc - v;   // exclusive prefix
}

// gathered gate+up GEMM per expert, fused SiLU*up*weight -> hmid
// grid: (I_DIM/64, NEXP), block 256
__global__ __launch_bounds__(256) void gateup_kernel(
    const float* __restrict__ x,
    const float* __restrict__ Wg, const float* __restrict__ Wu,
    const int* __restrict__ counts, const int* __restrict__ offsets,
    const int* __restrict__ lists, const float* __restrict__ wlist,
    float* __restrict__ hmid)
{
    const int e = blockIdx.y;
    const int itile = blockIdx.x;             // 0..11
    const int count = counts[e];
    if (count == 0) return;
    const int off = offsets[e];

    __shared__ float Xs[32][33];              // +1 pad: Xs[ty][kk] bank-spread
    __shared__ float Wgs[32][64];
    __shared__ float Wus[32][64];

    const int tid = threadIdx.x;
    const int tx = tid & 15, ty = tid >> 4;

    const float* WgE = Wg + (size_t)e * H_DIM * I_DIM + itile * 64;
    const float* WuE = Wu + (size_t)e * H_DIM * I_DIM + itile * 64;

    for (int tt = 0; tt * 32 < count; ++tt) {
        float accg[2][4] = {}, accu[2][4] = {};
        for (int hh = 0; hh < H_DIM; hh += 32) {
            #pragma unroll
            for (int m2 = 0; m2 < 4; ++m2) {
                int li = tid + m2 * 256;
                int r = li >> 5, c = li & 31;
                int pos = tt * 32 + r;
                int pc = pos < count ? pos : count - 1;
                int tok = lists[e * NTOK + pc];
                Xs[r][c] = x[(size_t)tok * H_DIM + hh + c];
            }
            #pragma unroll
            for (int m2 = 0; m2 < 8; ++m2) {
                int li = tid + m2 * 256;
                int r = li >> 6, c = li & 63;
                Wgs[r][c] = WgE[(size_t)(hh + r) * I_DIM + c];
                Wus[r][c] = WuE[(size_t)(hh + r) * I_DIM + c];
            }
            __syncthreads();
            #pragma unroll
            for (int kk = 0; kk < 32; ++kk) {
                float x0 = Xs[ty][kk], x1 = Xs[ty + 16][kk];
                #pragma unroll
                for (int j = 0; j < 4; ++j) {
                    float wg = Wgs[kk][tx + 16 * j];
                    float wu = Wus[kk][tx + 16 * j];
                    accg[0][j] += x0 * wg; accg[1][j] += x1 * wg;
                    accu[0][j] += x0 * wu; accu[1][j] += x1 * wu;
                }
            }
            __syncthreads();
        }
        #pragma unroll
        for (int rr = 0; rr < 2; ++rr) {
            int pos = tt * 32 + ty + rr * 16;
            if (pos < count) {
                float w = wlist[e * NTOK + pos];
                size_t base = (size_t)(off + pos) * I_DIM + itile * 64;
                #pragma unroll
                for (int j = 0; j < 4; ++j) {
                    float g = accg[rr][j], u = accu[rr][j];
                    float sig = 1.f / (1.f + __expf(-g));
                    hmid[base + tx + 16 * j] = g * sig * u * w;
                }
            }
        }
    }
}

// down GEMM per expert, atomic scatter-add into out
// grid: (H_DIM/64, NEXP), block 256
__global__ __launch_bounds__(256) void down_kernel(
    const float* __restrict__ hmid, const float* __restrict__ Wd,
    const int* __restrict__ counts, const int* __restrict__ offsets,
    const int* __restrict__ lists, float* __restrict__ out)
{
    const int e = blockIdx.y;
    const int htile = blockIdx.x;             // 0..31
    const int count = counts[e];
    if (count == 0) return;
    const int off = offsets[e];

    __shared__ float Hs[32][33];
    __shared__ float Ws[32][64];

    const int tid = threadIdx.x;
    const int tx = tid & 15, ty = tid >> 4;

    const float* WdE = Wd + (size_t)e * I_DIM * H_DIM + htile * 64;

    for (int tt = 0; tt * 32 < count; ++tt) {
        float acc[2][4] = {};
        for (int ii = 0; ii < I_DIM; ii += 32) {
            #pragma unroll
            for (int m2 = 0; m2 < 4; ++m2) {
                int li = tid + m2 * 256;
                int r = li >> 5, c = li & 31;
                int pos = tt * 32 + r;
                int pc = pos < count ? pos : count - 1;
                Hs[r][c] = hmid[(size_t)(off + pc) * I_DIM + ii + c];
            }
            #pragma unroll
            for (int m2 = 0; m2 < 8; ++m2) {
                int li = tid + m2 * 256;
                int r = li >> 6, c = li & 63;
                Ws[r][c] = WdE[(size_t)(ii + r) * H_DIM + c];
            }
            __syncthreads();
            #pragma unroll
            for (int kk = 0; kk < 32; ++kk) {
                float h0 = Hs[ty][kk], h1 = Hs[ty + 16][kk];
                #pragma unroll
                for (int j = 0; j < 4; ++j) {
                    float w = Ws[kk][tx + 16 * j];
                    acc[0][j] += h0 * w; acc[1][j] += h1 * w;
                }
            }
            __syncthreads();
        }
        #pragma unroll
        for (int rr = 0; rr < 2; ++rr) {
            int pos = tt * 32 + ty + rr * 16;
            if (pos < count) {
                int tok = lists[e * NTOK + pos];
                #pragma unroll
                for (int j = 0; j < 4; ++j)
                    atomicAdd(&out[(size_t)tok * H_DIM + htile * 64 + tx + 16 * j],
                              acc[rr][j]);
            }
        }
    }
}

extern "C" void kernel_launch(void* const* d_in, const int* in_sizes, int n_in,
                              void* d_out, int out_size, void* d_ws, size_t ws_size,
                              hipStream_t stream) {
    const float* x  = (const float*)d_in[0];   // [1,1024,2048]
    const float* Wr = (const float*)d_in[1];   // [2048,64]
    const float* Wg = (const float*)d_in[2];   // [64,2048,768]
    const float* Wu = (const float*)d_in[3];   // [64,2048,768]
    const float* Wd = (const float*)d_in[4];   // [64,768,2048]
    float* out = (float*)d_out;                // [1,1024,2048]

    char* ws = (char*)d_ws;
    int*   topk_idx = (int*)  (ws + 0);
    float* topk_w   = (float*)(ws + 32768);
    int*   counts   = (int*)  (ws + 65536);
    int*   offsets  = (int*)  (ws + 65792);
    int*   lists    = (int*)  (ws + 66048);
    float* wlist    = (float*)(ws + 328192);
    float* hmid     = (float*)(ws + 590336);

    const int nout = NTOK * H_DIM;
    hipLaunchKernelGGL(zero_kernel, dim3((nout + 255) / 256), dim3(256), 0, stream,
                       out, nout);
    hipLaunchKernelGGL(router_kernel, dim3(NTOK), dim3(64), 0, stream,
                       x, Wr, topk_idx, topk_w);
    hipLaunchKernelGGL(listbuild_kernel, dim3(NEXP), dim3(64), 0, stream,
                       topk_idx, topk_w, counts, lists, wlist);
    hipLaunchKernelGGL(scan_kernel, dim3(1), dim3(64), 0, stream,
                       counts, offsets);
    hipLaunchKernelGGL(gateup_kernel, dim3(I_DIM / 64, NEXP), dim3(256), 0, stream,
                       x, Wg, Wu, counts, offsets, lists, wlist, hmid);
    hipLaunchKernelGGL(down_kernel, dim3(H_DIM / 64, NEXP), dim3(256), 0, stream,
                       hmid, Wd, counts, offsets, lists, out);
}

// Round 2
// 885.053 us; speedup vs baseline: 3.0521x; 3.0521x over previous
//
#include <hip/hip_runtime.h>
#include <hip/hip_bf16.h>

#define H_DIM 2048
#define I_DIM 768
#define NEXP 64
#define TOPK 8
#define NTOK 1024   // B*S
#define BM 256      // token tile (count ~128 => single chunk)
#define BKS 32      // K per step

typedef float f32x4 __attribute__((ext_vector_type(4)));
typedef short bf16v8 __attribute__((ext_vector_type(8)));   // 8 bf16 in 4 VGPRs
typedef unsigned int u32;

// ---------------- workspace layout (bytes) ----------------
// topk_idx : int   [NTOK*TOPK]           @ 0
// topk_w   : float [NTOK*TOPK]           @ 32768
// counts   : int   [NEXP]                @ 65536
// offsets  : int   [NEXP]                @ 65792
// lists    : int   [NEXP*NTOK]           @ 66048
// wlist    : float [NEXP*NTOK]           @ 328192
// hmid     : bf16  [NTOK*TOPK * I_DIM]   @ 590336  (12.6 MB)

__device__ inline unsigned short f2bf(float f) {
    union { float f; u32 u; } v; v.f = f;
    u32 r = (v.u + 0x7FFFu + ((v.u >> 16) & 1u)) >> 16;
    return (unsigned short)r;
}
__device__ inline u32 pack2(float a, float b) {
    return (u32)f2bf(a) | ((u32)f2bf(b) << 16);
}

__global__ void zero_kernel(float* p, int n) {
    int i = blockIdx.x * blockDim.x + threadIdx.x;
    if (i < n) p[i] = 0.f;
}

// one block per token, 64 threads (one per expert) -- unchanged (passed R1)
__global__ __launch_bounds__(64) void router_kernel(
    const float* __restrict__ x, const float* __restrict__ Wr,
    int* __restrict__ topk_idx, float* __restrict__ topk_w)
{
    const int t = blockIdx.x;
    const int e = threadIdx.x;
    __shared__ float xs[H_DIM];

    const float* xrow = x + (size_t)t * H_DIM;
    #pragma unroll
    for (int m = 0; m < H_DIM / 64; ++m) xs[m * 64 + e] = xrow[m * 64 + e];
    __syncthreads();

    float acc = 0.f;
    #pragma unroll 8
    for (int h = 0; h < H_DIM; ++h) acc += xs[h] * Wr[(size_t)h * NEXP + e];

    float m = acc;
    #pragma unroll
    for (int o = 32; o > 0; o >>= 1) m = fmaxf(m, __shfl_xor(m, o));
    float p = __expf(acc - m);
    float s = p;
    #pragma unroll
    for (int o = 32; o > 0; o >>= 1) s += __shfl_xor(s, o);
    float prob = p / s;

    float myp = prob;
    float kw[TOPK]; int kid[TOPK]; float wsum = 0.f;
    #pragma unroll
    for (int k = 0; k < TOPK; ++k) {
        float v = myp; int bi = e;
        #pragma unroll
        for (int o = 32; o > 0; o >>= 1) {
            float ov = __shfl_xor(v, o);
            int   oi = __shfl_xor(bi, o);
            if (ov > v || (ov == v && oi < bi)) { v = ov; bi = oi; }
        }
        kw[k] = v; kid[k] = bi; wsum += v;
        if (e == bi) myp = -1.f;
    }
    if (e == 0) {
        float inv = 1.f / wsum;
        #pragma unroll
        for (int k = 0; k < TOPK; ++k) {
            topk_idx[t * TOPK + k] = kid[k];
            topk_w[t * TOPK + k]   = kw[k] * inv;
        }
    }
}

__global__ __launch_bounds__(64) void listbuild_kernel(
    const int* __restrict__ topk_idx, const float* __restrict__ topk_w,
    int* __restrict__ counts, int* __restrict__ lists, float* __restrict__ wlist)
{
    const int e = blockIdx.x;
    const int lane = threadIdx.x;
    int n = 0;
    for (int base = 0; base < NTOK * TOPK; base += 64) {
        int s = base + lane;
        int idx = topk_idx[s];
        bool match = (idx == e);
        unsigned long long mask = __ballot(match);
        int pre = __popcll(mask & ((1ull << lane) - 1ull));
        if (match) {
            lists[e * NTOK + n + pre] = s >> 3;
            wlist[e * NTOK + n + pre] = topk_w[s];
        }
        n += __popcll(mask);
    }
    if (lane == 0) counts[e] = n;
}

__global__ __launch_bounds__(64) void scan_kernel(
    const int* __restrict__ counts, int* __restrict__ offsets)
{
    int e = threadIdx.x;
    int v = counts[e];
    int xacc = v;
    #pragma unroll
    for (int o = 1; o < 64; o <<= 1) {
        int y = __shfl_up(xacc, o);
        if (e >= o) xacc += y;
    }
    offsets[e] = xacc - v;
}

// ---------------- MFMA gate+up: grid (I_DIM/64, NEXP), block 512 ----------------
__global__ __launch_bounds__(512) void gateup_kernel(
    const float* __restrict__ x,
    const float* __restrict__ Wg, const float* __restrict__ Wu,
    const int* __restrict__ counts, const int* __restrict__ offsets,
    const int* __restrict__ lists, const float* __restrict__ wlist,
    unsigned short* __restrict__ hmid)
{
    const int e = blockIdx.y;
    const int itile = blockIdx.x;
    const int count = counts[e];
    if (count == 0) return;
    const int off = offsets[e];
    const int i0 = itile * 64;

    __shared__ unsigned short Alds[BM][40];   // 20480 B, pad 40 (80 B rows)
    __shared__ u32 Bgl[64 * 20];              // [n][kpair] packed bf16x2, 5120 B
    __shared__ u32 Bul[64 * 20];

    const int tid  = threadIdx.x;
    const int lane = tid & 63;
    const int wid  = tid >> 6;
    const int wm   = wid >> 1, wn = wid & 1;  // wave grid 4x2
    const int kb   = lane >> 4;               // 0..3
    const int l15  = lane & 15;

    const float* WgE = Wg + (size_t)e * H_DIM * I_DIM + i0;
    const float* WuE = Wu + (size_t)e * H_DIM * I_DIM + i0;

    const int bn  = (tid & 31) * 2;           // B stage: n pair
    const int bkp = tid >> 5;                 // 0..15 (k pair)
    const int ar  = tid >> 1;                 // A stage: row
    const int ah  = (tid & 1) * 16;           // A stage: col half

    for (int mstart = 0; mstart < count; mstart += BM) {
        int pr = mstart + ar; if (pr >= count) pr = count - 1;
        const float* xrow = x + (size_t)lists[e * NTOK + pr] * H_DIM + ah;

        f32x4 accg[4][2], accu[4][2];
        #pragma unroll
        for (int i = 0; i < 4; ++i)
            #pragma unroll
            for (int j = 0; j < 2; ++j) {
                accg[i][j] = (f32x4){0.f, 0.f, 0.f, 0.f};
                accu[i][j] = (f32x4){0.f, 0.f, 0.f, 0.f};
            }

        #pragma unroll 2
        for (int hh = 0; hh < H_DIM; hh += BKS) {
            // ---- stage A: 256 rows x 32 cols fp32 -> bf16 ----
            {
                const float4* p = (const float4*)(xrow + hh);
                float4 v0 = p[0], v1 = p[1], v2 = p[2], v3 = p[3];
                u32 w0 = pack2(v0.x, v0.y), w1 = pack2(v0.z, v0.w);
                u32 w2 = pack2(v1.x, v1.y), w3 = pack2(v1.z, v1.w);
                u32 w4 = pack2(v2.x, v2.y), w5 = pack2(v2.z, v2.w);
                u32 w6 = pack2(v3.x, v3.y), w7 = pack2(v3.z, v3.w);
                uint4 lo = {w0, w1, w2, w3}, hi = {w4, w5, w6, w7};
                *(uint4*)&Alds[ar][ah]     = lo;
                *(uint4*)&Alds[ar][ah + 8] = hi;
            }
            // ---- stage B: 32 k-rows x 64 cols, transpose-pack ----
            {
                const float2* g0 = (const float2*)(WgE + (size_t)(hh + 2 * bkp)     * I_DIM + bn);
                const float2* g1 = (const float2*)(WgE + (size_t)(hh + 2 * bkp + 1) * I_DIM + bn);
                const float2* u0 = (const float2*)(WuE + (size_t)(hh + 2 * bkp)     * I_DIM + bn);
                const float2* u1 = (const float2*)(WuE + (size_t)(hh + 2 * bkp + 1) * I_DIM + bn);
                float2 a0 = *g0, a1 = *g1, b0 = *u0, b1 = *u1;
                Bgl[(bn)     * 20 + bkp] = pack2(a0.x, a1.x);
                Bgl[(bn + 1) * 20 + bkp] = pack2(a0.y, a1.y);
                Bul[(bn)     * 20 + bkp] = pack2(b0.x, b1.x);
                Bul[(bn + 1) * 20 + bkp] = pack2(b0.y, b1.y);
            }
            __syncthreads();

            bf16v8 af[4], bg[2], bu[2];
            #pragma unroll
            for (int mf = 0; mf < 4; ++mf)
                af[mf] = *(const bf16v8*)&Alds[wm * 64 + mf * 16 + l15][kb * 8];
            #pragma unroll
            for (int nf = 0; nf < 2; ++nf) {
                int n = wn * 32 + nf * 16 + l15;
                bg[nf] = *(const bf16v8*)&Bgl[n * 20 + kb * 4];
                bu[nf] = *(const bf16v8*)&Bul[n * 20 + kb * 4];
            }
            #pragma unroll
            for (int mf = 0; mf < 4; ++mf)
                #pragma unroll
                for (int nf = 0; nf < 2; ++nf) {
                    accg[mf][nf] = __builtin_amdgcn_mfma_f32_16x16x32_bf16(af[mf], bg[nf], accg[mf][nf], 0, 0, 0);
                    accu[mf][nf] = __builtin_amdgcn_mfma_f32_16x16x32_bf16(af[mf], bu[nf], accu[mf][nf], 0, 0, 0);
                }
            __syncthreads();
        }

        // ---- epilogue: silu(g)*u*w -> hmid (bf16) ----
        #pragma unroll
        for (int mf = 0; mf < 4; ++mf)
            #pragma unroll
            for (int nf = 0; nf < 2; ++nf)
                #pragma unroll
                for (int r = 0; r < 4; ++r) {
                    int ml  = wm * 64 + mf * 16 + (lane >> 4) * 4 + r;
                    int pos = mstart + ml;
                    if (pos < count) {
                        float wgt = wlist[e * NTOK + pos];
                        float g = accg[mf][nf][r], u = accu[mf][nf][r];
                        float s = 1.f / (1.f + __expf(-g));
                        float h = g * s * u * wgt;
                        hmid[(size_t)(off + pos) * I_DIM + i0 + wn * 32 + nf * 16 + l15] = f2bf(h);
                    }
                }
    }
}

// ---------------- MFMA down: grid (H_DIM/64, NEXP), block 512 ----------------
__global__ __launch_bounds__(512) void down_kernel(
    const unsigned short* __restrict__ hmid, const float* __restrict__ Wd,
    const int* __restrict__ counts, const int* __restrict__ offsets,
    const int* __restrict__ lists, float* __restrict__ out)
{
    const int e = blockIdx.y;
    const int htile = blockIdx.x;
    const int count = counts[e];
    if (count == 0) return;
    const int off = offsets[e];
    const int h0 = htile * 64;

    __shared__ unsigned short Alds[BM][40];
    __shared__ u32 Bdl[64 * 20];

    const int tid  = threadIdx.x;
    const int lane = tid & 63;
    const int wid  = tid >> 6;
    const int wm   = wid >> 1, wn = wid & 1;
    const int kb   = lane >> 4;
    const int l15  = lane & 15;

    const float* WdE = Wd + (size_t)e * I_DIM * H_DIM + h0;

    const int bn  = (tid & 31) * 2;
    const int bkp = tid >> 5;
    const int ar  = tid >> 1;
    const int ah  = (tid & 1) * 16;

    for (int mstart = 0; mstart < count; mstart += BM) {
        int pr = mstart + ar; if (pr >= count) pr = count - 1;
        const unsigned short* hrow = hmid + (size_t)(off + pr) * I_DIM + ah;

        f32x4 acc[4][2];
        #pragma unroll
        for (int i = 0; i < 4; ++i)
            #pragma unroll
            for (int j = 0; j < 2; ++j) acc[i][j] = (f32x4){0.f, 0.f, 0.f, 0.f};

        #pragma unroll 2
        for (int ii = 0; ii < I_DIM; ii += BKS) {
            {
                const uint4* p = (const uint4*)(hrow + ii);
                uint4 lo = p[0], hi = p[1];
                *(uint4*)&Alds[ar][ah]     = lo;
                *(uint4*)&Alds[ar][ah + 8] = hi;
            }
            {
                const float2* g0 = (const float2*)(WdE + (size_t)(ii + 2 * bkp)     * H_DIM + bn);
                const float2* g1 = (const float2*)(WdE + (size_t)(ii + 2 * bkp + 1) * H_DIM + bn);
                float2 a0 = *g0, a1 = *g1;
                Bdl[(bn)     * 20 + bkp] = pack2(a0.x, a1.x);
                Bdl[(bn + 1) * 20 + bkp] = pack2(a0.y, a1.y);
            }
            __syncthreads();

            bf16v8 af[4], bd[2];
            #pragma unroll
            for (int mf = 0; mf < 4; ++mf)
                af[mf] = *(const bf16v8*)&Alds[wm * 64 + mf * 16 + l15][kb * 8];
            #pragma unroll
            for (int nf = 0; nf < 2; ++nf) {
                int n = wn * 32 + nf * 16 + l15;
                bd[nf] = *(const bf16v8*)&Bdl[n * 20 + kb * 4];
            }
            #pragma unroll
            for (int mf = 0; mf < 4; ++mf)
                #pragma unroll
                for (int nf = 0; nf < 2; ++nf)
                    acc[mf][nf] = __builtin_amdgcn_mfma_f32_16x16x32_bf16(af[mf], bd[nf], acc[mf][nf], 0, 0, 0);
            __syncthreads();
        }

        #pragma unroll
        for (int mf = 0; mf < 4; ++mf)
            #pragma unroll
            for (int nf = 0; nf < 2; ++nf)
                #pragma unroll
                for (int r = 0; r < 4; ++r) {
                    int ml  = wm * 64 + mf * 16 + (lane >> 4) * 4 + r;
                    int pos = mstart + ml;
                    if (pos < count) {
                        int tok = lists[e * NTOK + pos];
                        atomicAdd(&out[(size_t)tok * H_DIM + h0 + wn * 32 + nf * 16 + l15],
                                  acc[mf][nf][r]);
                    }
                }
    }
}

extern "C" void kernel_launch(void* const* d_in, const int* in_sizes, int n_in,
                              void* d_out, int out_size, void* d_ws, size_t ws_size,
                              hipStream_t stream) {
    const float* x  = (const float*)d_in[0];
    const float* Wr = (const float*)d_in[1];
    const float* Wg = (const float*)d_in[2];
    const float* Wu = (const float*)d_in[3];
    const float* Wd = (const float*)d_in[4];
    float* out = (float*)d_out;

    char* ws = (char*)d_ws;
    int*   topk_idx = (int*)  (ws + 0);
    float* topk_w   = (float*)(ws + 32768);
    int*   counts   = (int*)  (ws + 65536);
    int*   offsets  = (int*)  (ws + 65792);
    int*   lists    = (int*)  (ws + 66048);
    float* wlist    = (float*)(ws + 328192);
    unsigned short* hmid = (unsigned short*)(ws + 590336);

    const int nout = NTOK * H_DIM;
    hipLaunchKernelGGL(zero_kernel, dim3((nout + 255) / 256), dim3(256), 0, stream,
                       out, nout);
    hipLaunchKernelGGL(router_kernel, dim3(NTOK), dim3(64), 0, stream,
                       x, Wr, topk_idx, topk_w);
    hipLaunchKernelGGL(listbuild_kernel, dim3(NEXP), dim3(64), 0, stream,
                       topk_idx, topk_w, counts, lists, wlist);
    hipLaunchKernelGGL(scan_kernel, dim3(1), dim3(64), 0, stream,
                       counts, offsets);
    hipLaunchKernelGGL(gateup_kernel, dim3(I_DIM / 64, NEXP), dim3(512), 0, stream,
                       x, Wg, Wu, counts, offsets, lists, wlist, hmid);
    hipLaunchKernelGGL(down_kernel, dim3(H_DIM / 64, NEXP), dim3(512), 0, stream,
                       hmid, Wd, counts, offsets, lists, out);
}

// Round 3
// 644.949 us; speedup vs baseline: 4.1884x; 1.3723x over previous
//
#include <hip/hip_runtime.h>
#include <hip/hip_bf16.h>

#define H_DIM 2048
#define I_DIM 768
#define NEXP 64
#define TOPK 8
#define NTOK 1024   // B*S
#define BM 256      // token tile (count ~128+-11 => single chunk, no weight re-stream)
#define BKS 32      // K per step

typedef float f32x4 __attribute__((ext_vector_type(4)));
typedef short bf16v8 __attribute__((ext_vector_type(8)));   // 8 bf16 in 4 VGPRs
typedef unsigned int u32;

// ---------------- workspace layout (bytes) ----------------
// topk_idx : int   [NTOK*TOPK]           @ 0
// topk_w   : float [NTOK*TOPK]           @ 32768
// counts   : int   [NEXP]                @ 65536
// offsets  : int   [NEXP]                @ 65792
// lists    : int   [NEXP*NTOK]           @ 66048
// wlist    : float [NEXP*NTOK]           @ 328192
// hmid     : bf16  [NTOK*TOPK * I_DIM]   @ 590336  (12.6 MB)

__device__ inline unsigned short f2bf(float f) {
    union { float f; u32 u; } v; v.f = f;
    u32 r = (v.u + 0x7FFFu + ((v.u >> 16) & 1u)) >> 16;
    return (unsigned short)r;
}
__device__ inline u32 pack2(float a, float b) {
    return (u32)f2bf(a) | ((u32)f2bf(b) << 16);
}

__global__ void zero_kernel(float* p, int n) {
    int i = blockIdx.x * blockDim.x + threadIdx.x;
    if (i < n) p[i] = 0.f;
}

// one block per token, 64 threads (one per expert) -- unchanged (verified R1/R2)
__global__ __launch_bounds__(64) void router_kernel(
    const float* __restrict__ x, const float* __restrict__ Wr,
    int* __restrict__ topk_idx, float* __restrict__ topk_w)
{
    const int t = blockIdx.x;
    const int e = threadIdx.x;
    __shared__ float xs[H_DIM];

    const float* xrow = x + (size_t)t * H_DIM;
    #pragma unroll
    for (int m = 0; m < H_DIM / 64; ++m) xs[m * 64 + e] = xrow[m * 64 + e];
    __syncthreads();

    float acc = 0.f;
    #pragma unroll 8
    for (int h = 0; h < H_DIM; ++h) acc += xs[h] * Wr[(size_t)h * NEXP + e];

    float m = acc;
    #pragma unroll
    for (int o = 32; o > 0; o >>= 1) m = fmaxf(m, __shfl_xor(m, o));
    float p = __expf(acc - m);
    float s = p;
    #pragma unroll
    for (int o = 32; o > 0; o >>= 1) s += __shfl_xor(s, o);
    float prob = p / s;

    float myp = prob;
    float kw[TOPK]; int kid[TOPK]; float wsum = 0.f;
    #pragma unroll
    for (int k = 0; k < TOPK; ++k) {
        float v = myp; int bi = e;
        #pragma unroll
        for (int o = 32; o > 0; o >>= 1) {
            float ov = __shfl_xor(v, o);
            int   oi = __shfl_xor(bi, o);
            if (ov > v || (ov == v && oi < bi)) { v = ov; bi = oi; }
        }
        kw[k] = v; kid[k] = bi; wsum += v;
        if (e == bi) myp = -1.f;
    }
    if (e == 0) {
        float inv = 1.f / wsum;
        #pragma unroll
        for (int k = 0; k < TOPK; ++k) {
            topk_idx[t * TOPK + k] = kid[k];
            topk_w[t * TOPK + k]   = kw[k] * inv;
        }
    }
}

__global__ __launch_bounds__(64) void listbuild_kernel(
    const int* __restrict__ topk_idx, const float* __restrict__ topk_w,
    int* __restrict__ counts, int* __restrict__ lists, float* __restrict__ wlist)
{
    const int e = blockIdx.x;
    const int lane = threadIdx.x;
    int n = 0;
    for (int base = 0; base < NTOK * TOPK; base += 64) {
        int s = base + lane;
        int idx = topk_idx[s];
        bool match = (idx == e);
        unsigned long long mask = __ballot(match);
        int pre = __popcll(mask & ((1ull << lane) - 1ull));
        if (match) {
            lists[e * NTOK + n + pre] = s >> 3;
            wlist[e * NTOK + n + pre] = topk_w[s];
        }
        n += __popcll(mask);
    }
    if (lane == 0) counts[e] = n;
}

__global__ __launch_bounds__(64) void scan_kernel(
    const int* __restrict__ counts, int* __restrict__ offsets)
{
    int e = threadIdx.x;
    int v = counts[e];
    int xacc = v;
    #pragma unroll
    for (int o = 1; o < 64; o <<= 1) {
        int y = __shfl_up(xacc, o);
        if (e >= o) xacc += y;
    }
    offsets[e] = xacc - v;
}

// ---------------- MFMA gate+up with reg-prefetch pipeline ----------------
// grid (I_DIM/64, NEXP), block 512
__global__ __launch_bounds__(512) void gateup_kernel(
    const float* __restrict__ x,
    const float* __restrict__ Wg, const float* __restrict__ Wu,
    const int* __restrict__ counts, const int* __restrict__ offsets,
    const int* __restrict__ lists, const float* __restrict__ wlist,
    unsigned short* __restrict__ hmid)
{
    const int e = blockIdx.y;
    const int itile = blockIdx.x;
    const int count = counts[e];
    if (count == 0) return;
    const int off = offsets[e];
    const int i0 = itile * 64;

    __shared__ unsigned short Alds[BM][40];   // 20480 B
    __shared__ u32 Bgl[64 * 20];              // 5120 B
    __shared__ u32 Bul[64 * 20];

    const int tid  = threadIdx.x;
    const int lane = tid & 63;
    const int wid  = tid >> 6;
    const int wm   = wid >> 1, wn = wid & 1;  // wave grid 4x2
    const int kb   = lane >> 4;
    const int l15  = lane & 15;

    const float* WgE = Wg + (size_t)e * H_DIM * I_DIM + i0;
    const float* WuE = Wu + (size_t)e * H_DIM * I_DIM + i0;

    const int bn  = (tid & 31) * 2;           // B stage: n pair
    const int bkp = tid >> 5;                 // 0..15 (k pair)
    const int ar  = tid >> 1;                 // A stage: row
    const int ah  = (tid & 1) * 16;           // A stage: col half

    for (int mstart = 0; mstart < count; mstart += BM) {
        int pr = mstart + ar; if (pr >= count) pr = count - 1;
        const float* xrow = x + (size_t)lists[e * NTOK + pr] * H_DIM + ah;
        const bool mact = (mstart + wm * 64) < count;   // wave M-tile live?

        f32x4 accg[4][2], accu[4][2];
        #pragma unroll
        for (int i = 0; i < 4; ++i)
            #pragma unroll
            for (int j = 0; j < 2; ++j) {
                accg[i][j] = (f32x4){0.f, 0.f, 0.f, 0.f};
                accu[i][j] = (f32x4){0.f, 0.f, 0.f, 0.f};
            }

        // prefetch registers
        float4 pA0, pA1, pA2, pA3;
        float2 pG0, pG1, pU0, pU1;

#define GU_LOAD(h)                                                              \
        {                                                                       \
            const float4* p_ = (const float4*)(xrow + (h));                     \
            pA0 = p_[0]; pA1 = p_[1]; pA2 = p_[2]; pA3 = p_[3];                 \
            pG0 = *(const float2*)(WgE + (size_t)((h) + 2 * bkp)     * I_DIM + bn); \
            pG1 = *(const float2*)(WgE + (size_t)((h) + 2 * bkp + 1) * I_DIM + bn); \
            pU0 = *(const float2*)(WuE + (size_t)((h) + 2 * bkp)     * I_DIM + bn); \
            pU1 = *(const float2*)(WuE + (size_t)((h) + 2 * bkp + 1) * I_DIM + bn); \
        }

        GU_LOAD(0);

        #pragma unroll 2
        for (int hh = 0; hh < H_DIM; hh += BKS) {
            // ---- convert + store staged regs to LDS (drains vmcnt) ----
            {
                u32 w0 = pack2(pA0.x, pA0.y), w1 = pack2(pA0.z, pA0.w);
                u32 w2 = pack2(pA1.x, pA1.y), w3 = pack2(pA1.z, pA1.w);
                u32 w4 = pack2(pA2.x, pA2.y), w5 = pack2(pA2.z, pA2.w);
                u32 w6 = pack2(pA3.x, pA3.y), w7 = pack2(pA3.z, pA3.w);
                uint4 lo = {w0, w1, w2, w3}, hi = {w4, w5, w6, w7};
                *(uint4*)&Alds[ar][ah]     = lo;
                *(uint4*)&Alds[ar][ah + 8] = hi;
                Bgl[(bn)     * 20 + bkp] = pack2(pG0.x, pG1.x);
                Bgl[(bn + 1) * 20 + bkp] = pack2(pG0.y, pG1.y);
                Bul[(bn)     * 20 + bkp] = pack2(pU0.x, pU1.x);
                Bul[(bn + 1) * 20 + bkp] = pack2(pU0.y, pU1.y);
            }
            __syncthreads();

            // ---- issue next K-step's global loads (in flight during MFMA) ----
            if (hh + BKS < H_DIM) GU_LOAD(hh + BKS);

            // ---- MFMA phase on current LDS tile ----
            if (mact) {
                bf16v8 af[4], bg[2], bu[2];
                #pragma unroll
                for (int mf = 0; mf < 4; ++mf)
                    af[mf] = *(const bf16v8*)&Alds[wm * 64 + mf * 16 + l15][kb * 8];
                #pragma unroll
                for (int nf = 0; nf < 2; ++nf) {
                    int n = wn * 32 + nf * 16 + l15;
                    bg[nf] = *(const bf16v8*)&Bgl[n * 20 + kb * 4];
                    bu[nf] = *(const bf16v8*)&Bul[n * 20 + kb * 4];
                }
                #pragma unroll
                for (int mf = 0; mf < 4; ++mf)
                    #pragma unroll
                    for (int nf = 0; nf < 2; ++nf) {
                        accg[mf][nf] = __builtin_amdgcn_mfma_f32_16x16x32_bf16(af[mf], bg[nf], accg[mf][nf], 0, 0, 0);
                        accu[mf][nf] = __builtin_amdgcn_mfma_f32_16x16x32_bf16(af[mf], bu[nf], accu[mf][nf], 0, 0, 0);
                    }
            }
            __syncthreads();
        }
#undef GU_LOAD

        // ---- epilogue: silu(g)*u*w -> hmid (bf16) ----
        if (mact) {
            #pragma unroll
            for (int mf = 0; mf < 4; ++mf)
                #pragma unroll
                for (int nf = 0; nf < 2; ++nf)
                    #pragma unroll
                    for (int r = 0; r < 4; ++r) {
                        int ml  = wm * 64 + mf * 16 + (lane >> 4) * 4 + r;
                        int pos = mstart + ml;
                        if (pos < count) {
                            float wgt = wlist[e * NTOK + pos];
                            float g = accg[mf][nf][r], u = accu[mf][nf][r];
                            float s = 1.f / (1.f + __expf(-g));
                            float h = g * s * u * wgt;
                            hmid[(size_t)(off + pos) * I_DIM + i0 + wn * 32 + nf * 16 + l15] = f2bf(h);
                        }
                    }
        }
    }
}

// ---------------- MFMA down with reg-prefetch pipeline ----------------
// grid (H_DIM/64, NEXP), block 512
__global__ __launch_bounds__(512) void down_kernel(
    const unsigned short* __restrict__ hmid, const float* __restrict__ Wd,
    const int* __restrict__ counts, const int* __restrict__ offsets,
    const int* __restrict__ lists, float* __restrict__ out)
{
    const int e = blockIdx.y;
    const int htile = blockIdx.x;
    const int count = counts[e];
    if (count == 0) return;
    const int off = offsets[e];
    const int h0 = htile * 64;

    __shared__ unsigned short Alds[BM][40];
    __shared__ u32 Bdl[64 * 20];

    const int tid  = threadIdx.x;
    const int lane = tid & 63;
    const int wid  = tid >> 6;
    const int wm   = wid >> 1, wn = wid & 1;
    const int kb   = lane >> 4;
    const int l15  = lane & 15;

    const float* WdE = Wd + (size_t)e * I_DIM * H_DIM + h0;

    const int bn  = (tid & 31) * 2;
    const int bkp = tid >> 5;
    const int ar  = tid >> 1;
    const int ah  = (tid & 1) * 16;

    for (int mstart = 0; mstart < count; mstart += BM) {
        int pr = mstart + ar; if (pr >= count) pr = count - 1;
        const unsigned short* hrow = hmid + (size_t)(off + pr) * I_DIM + ah;
        const bool mact = (mstart + wm * 64) < count;

        f32x4 acc[4][2];
        #pragma unroll
        for (int i = 0; i < 4; ++i)
            #pragma unroll
            for (int j = 0; j < 2; ++j) acc[i][j] = (f32x4){0.f, 0.f, 0.f, 0.f};

        uint4 pH0, pH1;
        float2 pD0, pD1;

#define DN_LOAD(k)                                                              \
        {                                                                       \
            const uint4* p_ = (const uint4*)(hrow + (k));                       \
            pH0 = p_[0]; pH1 = p_[1];                                           \
            pD0 = *(const float2*)(WdE + (size_t)((k) + 2 * bkp)     * H_DIM + bn); \
            pD1 = *(const float2*)(WdE + (size_t)((k) + 2 * bkp + 1) * H_DIM + bn); \
        }

        DN_LOAD(0);

        #pragma unroll 2
        for (int ii = 0; ii < I_DIM; ii += BKS) {
            {
                *(uint4*)&Alds[ar][ah]     = pH0;
                *(uint4*)&Alds[ar][ah + 8] = pH1;
                Bdl[(bn)     * 20 + bkp] = pack2(pD0.x, pD1.x);
                Bdl[(bn + 1) * 20 + bkp] = pack2(pD0.y, pD1.y);
            }
            __syncthreads();

            if (ii + BKS < I_DIM) DN_LOAD(ii + BKS);

            if (mact) {
                bf16v8 af[4], bd[2];
                #pragma unroll
                for (int mf = 0; mf < 4; ++mf)
                    af[mf] = *(const bf16v8*)&Alds[wm * 64 + mf * 16 + l15][kb * 8];
                #pragma unroll
                for (int nf = 0; nf < 2; ++nf) {
                    int n = wn * 32 + nf * 16 + l15;
                    bd[nf] = *(const bf16v8*)&Bdl[n * 20 + kb * 4];
                }
                #pragma unroll
                for (int mf = 0; mf < 4; ++mf)
                    #pragma unroll
                    for (int nf = 0; nf < 2; ++nf)
                        acc[mf][nf] = __builtin_amdgcn_mfma_f32_16x16x32_bf16(af[mf], bd[nf], acc[mf][nf], 0, 0, 0);
            }
            __syncthreads();
        }
#undef DN_LOAD

        if (mact) {
            #pragma unroll
            for (int mf = 0; mf < 4; ++mf)
                #pragma unroll
                for (int nf = 0; nf < 2; ++nf)
                    #pragma unroll
                    for (int r = 0; r < 4; ++r) {
                        int ml  = wm * 64 + mf * 16 + (lane >> 4) * 4 + r;
                        int pos = mstart + ml;
                        if (pos < count) {
                            int tok = lists[e * NTOK + pos];
                            atomicAdd(&out[(size_t)tok * H_DIM + h0 + wn * 32 + nf * 16 + l15],
                                      acc[mf][nf][r]);
                        }
                    }
        }
    }
}

extern "C" void kernel_launch(void* const* d_in, const int* in_sizes, int n_in,
                              void* d_out, int out_size, void* d_ws, size_t ws_size,
                              hipStream_t stream) {
    const float* x  = (const float*)d_in[0];
    const float* Wr = (const float*)d_in[1];
    const float* Wg = (const float*)d_in[2];
    const float* Wu = (const float*)d_in[3];
    const float* Wd = (const float*)d_in[4];
    float* out = (float*)d_out;

    char* ws = (char*)d_ws;
    int*   topk_idx = (int*)  (ws + 0);
    float* topk_w   = (float*)(ws + 32768);
    int*   counts   = (int*)  (ws + 65536);
    int*   offsets  = (int*)  (ws + 65792);
    int*   lists    = (int*)  (ws + 66048);
    float* wlist    = (float*)(ws + 328192);
    unsigned short* hmid = (unsigned short*)(ws + 590336);

    const int nout = NTOK * H_DIM;
    hipLaunchKernelGGL(zero_kernel, dim3((nout + 255) / 256), dim3(256), 0, stream,
                       out, nout);
    hipLaunchKernelGGL(router_kernel, dim3(NTOK), dim3(64), 0, stream,
                       x, Wr, topk_idx, topk_w);
    hipLaunchKernelGGL(listbuild_kernel, dim3(NEXP), dim3(64), 0, stream,
                       topk_idx, topk_w, counts, lists, wlist);
    hipLaunchKernelGGL(scan_kernel, dim3(1), dim3(64), 0, stream,
                       counts, offsets);
    hipLaunchKernelGGL(gateup_kernel, dim3(I_DIM / 64, NEXP), dim3(512), 0, stream,
                       x, Wg, Wu, counts, offsets, lists, wlist, hmid);
    hipLaunchKernelGGL(down_kernel, dim3(H_DIM / 64, NEXP), dim3(512), 0, stream,
                       hmid, Wd, counts, offsets, lists, out);
}

// Round 5
// 561.416 us; speedup vs baseline: 4.8115x; 1.1488x over previous
//
#include <hip/hip_runtime.h>
#include <hip/hip_bf16.h>

#define H_DIM 2048
#define I_DIM 768
#define NEXP 64
#define TOPK 8
#define NTOK 1024   // B*S
#define BM 256      // token tile (count ~128+-11 => single chunk)
#define BKS 32      // K per step

typedef float f32x4 __attribute__((ext_vector_type(4)));
typedef float f32x2 __attribute__((ext_vector_type(2)));    // for nontemporal loads
typedef unsigned int u32x4 __attribute__((ext_vector_type(4)));
typedef short bf16v8 __attribute__((ext_vector_type(8)));   // 8 bf16 in 4 VGPRs
typedef unsigned int u32;

// ---------------- workspace layout (bytes) ----------------
// topk_idx : int   [NTOK*TOPK]           @ 0
// topk_w   : float [NTOK*TOPK]           @ 32768
// counts   : int   [NEXP]                @ 65536
// offsets  : int   [NEXP]                @ 65792
// lists    : int   [NEXP*NTOK]           @ 66048
// wlist    : float [NEXP*NTOK]           @ 328192
// hmid     : bf16  [NTOK*TOPK * I_DIM]   @ 590336   (12.58 MB)
// xbf      : bf16  [NTOK * H_DIM]        @ 13173248 (4 MB)

__device__ inline unsigned short f2bf(float f) {
    union { float f; u32 u; } v; v.f = f;
    u32 r = (v.u + 0x7FFFu + ((v.u >> 16) & 1u)) >> 16;
    return (unsigned short)r;
}
__device__ inline u32 pack2(float a, float b) {
    return (u32)f2bf(a) | ((u32)f2bf(b) << 16);
}

__global__ void zero_kernel(float4* p, int n4) {
    int i = blockIdx.x * blockDim.x + threadIdx.x;
    if (i < n4) p[i] = (float4){0.f, 0.f, 0.f, 0.f};
}

// fp32 x -> bf16 copy (4 MB out; removes fp32 A-stream from the GEMMs)
__global__ void xconv_kernel(const float4* __restrict__ x, ushort4* __restrict__ xbf, int n4) {
    int i = blockIdx.x * blockDim.x + threadIdx.x;
    if (i < n4) {
        float4 v = x[i];
        ushort4 o;
        o.x = f2bf(v.x); o.y = f2bf(v.y); o.z = f2bf(v.z); o.w = f2bf(v.w);
        xbf[i] = o;
    }
}

// one block per token, 64 threads (one per expert) -- verified R1-R3
__global__ __launch_bounds__(64) void router_kernel(
    const float* __restrict__ x, const float* __restrict__ Wr,
    int* __restrict__ topk_idx, float* __restrict__ topk_w)
{
    const int t = blockIdx.x;
    const int e = threadIdx.x;
    __shared__ float xs[H_DIM];

    const float* xrow = x + (size_t)t * H_DIM;
    #pragma unroll
    for (int m = 0; m < H_DIM / 64; ++m) xs[m * 64 + e] = xrow[m * 64 + e];
    __syncthreads();

    float acc = 0.f;
    #pragma unroll 8
    for (int h = 0; h < H_DIM; ++h) acc += xs[h] * Wr[(size_t)h * NEXP + e];

    float m = acc;
    #pragma unroll
    for (int o = 32; o > 0; o >>= 1) m = fmaxf(m, __shfl_xor(m, o));
    float p = __expf(acc - m);
    float s = p;
    #pragma unroll
    for (int o = 32; o > 0; o >>= 1) s += __shfl_xor(s, o);
    float prob = p / s;

    float myp = prob;
    float kw[TOPK]; int kid[TOPK]; float wsum = 0.f;
    #pragma unroll
    for (int k = 0; k < TOPK; ++k) {
        float v = myp; int bi = e;
        #pragma unroll
        for (int o = 32; o > 0; o >>= 1) {
            float ov = __shfl_xor(v, o);
            int   oi = __shfl_xor(bi, o);
            if (ov > v || (ov == v && oi < bi)) { v = ov; bi = oi; }
        }
        kw[k] = v; kid[k] = bi; wsum += v;
        if (e == bi) myp = -1.f;
    }
    if (e == 0) {
        float inv = 1.f / wsum;
        #pragma unroll
        for (int k = 0; k < TOPK; ++k) {
            topk_idx[t * TOPK + k] = kid[k];
            topk_w[t * TOPK + k]   = kw[k] * inv;
        }
    }
}

__global__ __launch_bounds__(64) void listbuild_kernel(
    const int* __restrict__ topk_idx, const float* __restrict__ topk_w,
    int* __restrict__ counts, int* __restrict__ lists, float* __restrict__ wlist)
{
    const int e = blockIdx.x;
    const int lane = threadIdx.x;
    int n = 0;
    for (int base = 0; base < NTOK * TOPK; base += 64) {
        int s = base + lane;
        int idx = topk_idx[s];
        bool match = (idx == e);
        unsigned long long mask = __ballot(match);
        int pre = __popcll(mask & ((1ull << lane) - 1ull));
        if (match) {
            lists[e * NTOK + n + pre] = s >> 3;
            wlist[e * NTOK + n + pre] = topk_w[s];
        }
        n += __popcll(mask);
    }
    if (lane == 0) counts[e] = n;
}

__global__ __launch_bounds__(64) void scan_kernel(
    const int* __restrict__ counts, int* __restrict__ offsets)
{
    int e = threadIdx.x;
    int v = counts[e];
    int xacc = v;
    #pragma unroll
    for (int o = 1; o < 64; o <<= 1) {
        int y = __shfl_up(xacc, o);
        if (e >= o) xacc += y;
    }
    offsets[e] = xacc - v;
}

// ---------------- MFMA gate+up: grid 768 (xcd-swizzled), block 512 ----------------
__global__ __launch_bounds__(512) void gateup_kernel(
    const unsigned short* __restrict__ xbf,
    const float* __restrict__ Wg, const float* __restrict__ Wu,
    const int* __restrict__ counts, const int* __restrict__ offsets,
    const int* __restrict__ lists, const float* __restrict__ wlist,
    unsigned short* __restrict__ hmid)
{
    // bijective XCD-chunk swizzle: 768 = 8 * 96; itile fastest within chunk
    const int b  = blockIdx.x;
    const int wg = (b & 7) * 96 + (b >> 3);
    const int itile = wg % 12;
    const int e     = wg / 12;

    const int count = counts[e];
    if (count == 0) return;
    const int off = offsets[e];
    const int i0 = itile * 64;

    __shared__ unsigned short Alds[BM][40];   // 20480 B
    __shared__ u32 Bgl[64 * 20];              // 5120 B
    __shared__ u32 Bul[64 * 20];

    const int tid  = threadIdx.x;
    const int lane = tid & 63;
    const int wid  = tid >> 6;
    const int wm   = wid >> 1, wn = wid & 1;  // wave grid 4x2
    const int kb   = lane >> 4;
    const int l15  = lane & 15;

    const float* WgE = Wg + (size_t)e * H_DIM * I_DIM + i0;
    const float* WuE = Wu + (size_t)e * H_DIM * I_DIM + i0;

    const int bn  = (tid & 31) * 2;           // B stage: n pair
    const int bkp = tid >> 5;                 // 0..15 (k pair)
    const int ar  = tid >> 1;                 // A stage: row
    const int ah  = (tid & 1) * 16;           // A stage: col half (shorts)

    for (int mstart = 0; mstart < count; mstart += BM) {
        const int pr = mstart + ar;
        const bool aact = pr < count;                       // stage only live rows
        const unsigned short* xrow = xbf + (size_t)(aact ? lists[e * NTOK + pr] : 0) * H_DIM + ah;
        const bool mact = (mstart + wm * 64) < count;       // wave M-tile live?

        f32x4 accg[4][2], accu[4][2];
        #pragma unroll
        for (int i = 0; i < 4; ++i)
            #pragma unroll
            for (int j = 0; j < 2; ++j) {
                accg[i][j] = (f32x4){0.f, 0.f, 0.f, 0.f};
                accu[i][j] = (f32x4){0.f, 0.f, 0.f, 0.f};
            }

        u32x4 pA0, pA1;                                     // A prefetch (1-deep)
        f32x2 g0a, g1a, u0a, u1a;                           // B prefetch set 0
        f32x2 g0b, g1b, u0b, u1b;                           // B prefetch set 1

#define LOADA(h)                                                                \
        if (aact) {                                                             \
            const u32x4* pa_ = (const u32x4*)(xrow + (h));                      \
            pA0 = pa_[0]; pA1 = pa_[1];                                         \
        }
#define LOADB(G0,G1,U0,U1,h)                                                    \
        {                                                                       \
            G0 = __builtin_nontemporal_load((const f32x2*)(WgE + (size_t)((h) + 2 * bkp)     * I_DIM + bn)); \
            G1 = __builtin_nontemporal_load((const f32x2*)(WgE + (size_t)((h) + 2 * bkp + 1) * I_DIM + bn)); \
            U0 = __builtin_nontemporal_load((const f32x2*)(WuE + (size_t)((h) + 2 * bkp)     * I_DIM + bn)); \
            U1 = __builtin_nontemporal_load((const f32x2*)(WuE + (size_t)((h) + 2 * bkp + 1) * I_DIM + bn)); \
        }
#define STOREA()                                                                \
        if (aact) {                                                             \
            *(u32x4*)&Alds[ar][ah]     = pA0;                                   \
            *(u32x4*)&Alds[ar][ah + 8] = pA1;                                   \
        }
#define STOREB(G0,G1,U0,U1)                                                     \
        {                                                                       \
            Bgl[(bn)     * 20 + bkp] = pack2(G0.x, G1.x);                       \
            Bgl[(bn + 1) * 20 + bkp] = pack2(G0.y, G1.y);                       \
            Bul[(bn)     * 20 + bkp] = pack2(U0.x, U1.x);                       \
            Bul[(bn + 1) * 20 + bkp] = pack2(U0.y, U1.y);                       \
        }
#define MFMA_PHASE()                                                            \
        if (mact) {                                                             \
            bf16v8 af[4], bg[2], bu[2];                                         \
            _Pragma("unroll")                                                   \
            for (int mf = 0; mf < 4; ++mf)                                      \
                af[mf] = *(const bf16v8*)&Alds[wm * 64 + mf * 16 + l15][kb * 8];\
            _Pragma("unroll")                                                   \
            for (int nf = 0; nf < 2; ++nf) {                                    \
                int n = wn * 32 + nf * 16 + l15;                                \
                bg[nf] = *(const bf16v8*)&Bgl[n * 20 + kb * 4];                 \
                bu[nf] = *(const bf16v8*)&Bul[n * 20 + kb * 4];                 \
            }                                                                   \
            _Pragma("unroll")                                                   \
            for (int mf = 0; mf < 4; ++mf)                                      \
                _Pragma("unroll")                                               \
                for (int nf = 0; nf < 2; ++nf) {                                \
                    accg[mf][nf] = __builtin_amdgcn_mfma_f32_16x16x32_bf16(af[mf], bg[nf], accg[mf][nf], 0, 0, 0); \
                    accu[mf][nf] = __builtin_amdgcn_mfma_f32_16x16x32_bf16(af[mf], bu[nf], accu[mf][nf], 0, 0, 0); \
                }                                                               \
        }

        LOADB(g0a, g1a, u0a, u1a, 0);
        LOADB(g0b, g1b, u0b, u1b, BKS);
        LOADA(0);

        for (int hh = 0; hh < H_DIM; hh += 2 * BKS) {
            // even step: consumes B set0 (hh), A(hh)
            STOREA(); STOREB(g0a, g1a, u0a, u1a);
            __syncthreads();
            if (hh + 2 * BKS < H_DIM) LOADB(g0a, g1a, u0a, u1a, hh + 2 * BKS);
            LOADA(hh + BKS);
            MFMA_PHASE();
            __syncthreads();
            // odd step: consumes B set1 (hh+BKS), A(hh+BKS)
            STOREA(); STOREB(g0b, g1b, u0b, u1b);
            __syncthreads();
            if (hh + 3 * BKS < H_DIM) LOADB(g0b, g1b, u0b, u1b, hh + 3 * BKS);
            if (hh + 2 * BKS < H_DIM) LOADA(hh + 2 * BKS);
            MFMA_PHASE();
            __syncthreads();
        }
#undef LOADA
#undef LOADB
#undef STOREA
#undef STOREB
#undef MFMA_PHASE

        // ---- epilogue: silu(g)*u*w -> hmid (bf16) ----
        if (mact) {
            #pragma unroll
            for (int mf = 0; mf < 4; ++mf)
                #pragma unroll
                for (int nf = 0; nf < 2; ++nf)
                    #pragma unroll
                    for (int r = 0; r < 4; ++r) {
                        int ml  = wm * 64 + mf * 16 + (lane >> 4) * 4 + r;
                        int pos = mstart + ml;
                        if (pos < count) {
                            float wgt = wlist[e * NTOK + pos];
                            float g = accg[mf][nf][r], u = accu[mf][nf][r];
                            float s = 1.f / (1.f + __expf(-g));
                            float h = g * s * u * wgt;
                            hmid[(size_t)(off + pos) * I_DIM + i0 + wn * 32 + nf * 16 + l15] = f2bf(h);
                        }
                    }
        }
    }
}

// ---------------- MFMA down: grid 2048 (xcd-swizzled), block 512 ----------------
__global__ __launch_bounds__(512) void down_kernel(
    const unsigned short* __restrict__ hmid, const float* __restrict__ Wd,
    const int* __restrict__ counts, const int* __restrict__ offsets,
    const int* __restrict__ lists, float* __restrict__ out)
{
    // bijective XCD-chunk swizzle: 2048 = 8 * 256; htile fastest within chunk
    const int b  = blockIdx.x;
    const int wg = (b & 7) * 256 + (b >> 3);
    const int htile = wg % 32;
    const int e     = wg / 32;

    const int count = counts[e];
    if (count == 0) return;
    const int off = offsets[e];
    const int h0 = htile * 64;

    __shared__ unsigned short Alds[BM][40];
    __shared__ u32 Bdl[64 * 20];

    const int tid  = threadIdx.x;
    const int lane = tid & 63;
    const int wid  = tid >> 6;
    const int wm   = wid >> 1, wn = wid & 1;
    const int kb   = lane >> 4;
    const int l15  = lane & 15;

    const float* WdE = Wd + (size_t)e * I_DIM * H_DIM + h0;

    const int bn  = (tid & 31) * 2;
    const int bkp = tid >> 5;
    const int ar  = tid >> 1;
    const int ah  = (tid & 1) * 16;

    for (int mstart = 0; mstart < count; mstart += BM) {
        const int pr = mstart + ar;
        const bool aact = pr < count;
        const unsigned short* hrow = hmid + (size_t)(off + (aact ? pr : 0)) * I_DIM + ah;
        const bool mact = (mstart + wm * 64) < count;

        f32x4 acc[4][2];
        #pragma unroll
        for (int i = 0; i < 4; ++i)
            #pragma unroll
            for (int j = 0; j < 2; ++j) acc[i][j] = (f32x4){0.f, 0.f, 0.f, 0.f};

        u32x4 pH0, pH1;
        f32x2 d0a, d1a, d0b, d1b;

#define LOADA(k)                                                                \
        if (aact) {                                                             \
            const u32x4* p_ = (const u32x4*)(hrow + (k));                       \
            pH0 = p_[0]; pH1 = p_[1];                                           \
        }
#define LOADB(D0,D1,k)                                                          \
        {                                                                       \
            D0 = __builtin_nontemporal_load((const f32x2*)(WdE + (size_t)((k) + 2 * bkp)     * H_DIM + bn)); \
            D1 = __builtin_nontemporal_load((const f32x2*)(WdE + (size_t)((k) + 2 * bkp + 1) * H_DIM + bn)); \
        }
#define STOREA()                                                                \
        if (aact) {                                                             \
            *(u32x4*)&Alds[ar][ah]     = pH0;                                   \
            *(u32x4*)&Alds[ar][ah + 8] = pH1;                                   \
        }
#define STOREB(D0,D1)                                                           \
        {                                                                       \
            Bdl[(bn)     * 20 + bkp] = pack2(D0.x, D1.x);                       \
            Bdl[(bn + 1) * 20 + bkp] = pack2(D0.y, D1.y);                       \
        }
#define MFMA_PHASE()                                                            \
        if (mact) {                                                             \
            bf16v8 af[4], bd[2];                                                \
            _Pragma("unroll")                                                   \
            for (int mf = 0; mf < 4; ++mf)                                      \
                af[mf] = *(const bf16v8*)&Alds[wm * 64 + mf * 16 + l15][kb * 8];\
            _Pragma("unroll")                                                   \
            for (int nf = 0; nf < 2; ++nf) {                                    \
                int n = wn * 32 + nf * 16 + l15;                                \
                bd[nf] = *(const bf16v8*)&Bdl[n * 20 + kb * 4];                 \
            }                                                                   \
            _Pragma("unroll")                                                   \
            for (int mf = 0; mf < 4; ++mf)                                      \
                _Pragma("unroll")                                               \
                for (int nf = 0; nf < 2; ++nf)                                  \
                    acc[mf][nf] = __builtin_amdgcn_mfma_f32_16x16x32_bf16(af[mf], bd[nf], acc[mf][nf], 0, 0, 0); \
        }

        LOADB(d0a, d1a, 0);
        LOADB(d0b, d1b, BKS);
        LOADA(0);

        for (int ii = 0; ii < I_DIM; ii += 2 * BKS) {
            STOREA(); STOREB(d0a, d1a);
            __syncthreads();
            if (ii + 2 * BKS < I_DIM) LOADB(d0a, d1a, ii + 2 * BKS);
            LOADA(ii + BKS);
            MFMA_PHASE();
            __syncthreads();

            STOREA(); STOREB(d0b, d1b);
            __syncthreads();
            if (ii + 3 * BKS < I_DIM) LOADB(d0b, d1b, ii + 3 * BKS);
            if (ii + 2 * BKS < I_DIM) LOADA(ii + 2 * BKS);
            MFMA_PHASE();
            __syncthreads();
        }
#undef LOADA
#undef LOADB
#undef STOREA
#undef STOREB
#undef MFMA_PHASE

        if (mact) {
            #pragma unroll
            for (int mf = 0; mf < 4; ++mf)
                #pragma unroll
                for (int nf = 0; nf < 2; ++nf)
                    #pragma unroll
                    for (int r = 0; r < 4; ++r) {
                        int ml  = wm * 64 + mf * 16 + (lane >> 4) * 4 + r;
                        int pos = mstart + ml;
                        if (pos < count) {
                            int tok = lists[e * NTOK + pos];
                            atomicAdd(&out[(size_t)tok * H_DIM + h0 + wn * 32 + nf * 16 + l15],
                                      acc[mf][nf][r]);
                        }
                    }
        }
    }
}

extern "C" void kernel_launch(void* const* d_in, const int* in_sizes, int n_in,
                              void* d_out, int out_size, void* d_ws, size_t ws_size,
                              hipStream_t stream) {
    const float* x  = (const float*)d_in[0];
    const float* Wr = (const float*)d_in[1];
    const float* Wg = (const float*)d_in[2];
    const float* Wu = (const float*)d_in[3];
    const float* Wd = (const float*)d_in[4];
    float* out = (float*)d_out;

    char* ws = (char*)d_ws;
    int*   topk_idx = (int*)  (ws + 0);
    float* topk_w   = (float*)(ws + 32768);
    int*   counts   = (int*)  (ws + 65536);
    int*   offsets  = (int*)  (ws + 65792);
    int*   lists    = (int*)  (ws + 66048);
    float* wlist    = (float*)(ws + 328192);
    unsigned short* hmid = (unsigned short*)(ws + 590336);
    unsigned short* xbf  = (unsigned short*)(ws + 13173248);

    const int nout4 = NTOK * H_DIM / 4;
    hipLaunchKernelGGL(zero_kernel, dim3((nout4 + 255) / 256), dim3(256), 0, stream,
                       (float4*)out, nout4);
    hipLaunchKernelGGL(xconv_kernel, dim3((NTOK * H_DIM / 4 + 255) / 256), dim3(256), 0, stream,
                       (const float4*)x, (ushort4*)xbf, NTOK * H_DIM / 4);
    hipLaunchKernelGGL(router_kernel, dim3(NTOK), dim3(64), 0, stream,
                       x, Wr, topk_idx, topk_w);
    hipLaunchKernelGGL(listbuild_kernel, dim3(NEXP), dim3(64), 0, stream,
                       topk_idx, topk_w, counts, lists, wlist);
    hipLaunchKernelGGL(scan_kernel, dim3(1), dim3(64), 0, stream,
                       counts, offsets);
    hipLaunchKernelGGL(gateup_kernel, dim3(12 * NEXP), dim3(512), 0, stream,
                       xbf, Wg, Wu, counts, offsets, lists, wlist, hmid);
    hipLaunchKernelGGL(down_kernel, dim3(32 * NEXP), dim3(512), 0, stream,
                       hmid, Wd, counts, offsets, lists, out);
}